// Round 6
// baseline (120.257 us; speedup 1.0000x reference)
//
#include <hip/hip_runtime.h>

#define B_TOT 4096
#define BPB   2                 // batches per block
#define NBLK  (B_TOT / BPB)     // 2048 blocks

__global__ __launch_bounds__(256) void energy_kernel(
    const float* __restrict__ grid,
    const float* __restrict__ hints,
    const float* __restrict__ w_g,
    const float* __restrict__ w_h,
    float* __restrict__ ws)
{
    const int tid  = threadIdx.x;
    const int lane = tid & 63;
    const int wv   = tid >> 6;
    const int b0   = blockIdx.x * BPB;

    __shared__ float  target[2][2][64];   // [parity][row/col][64]
    __shared__ float4 colp4[2][4][16];    // [parity][wave][16]
    __shared__ float  red[4];

    // ---- weights: once per block (identical elements reused for both batches)
    const float4 wh0 = *(const float4*)(w_h + 8 * tid);
    const float4 wh1 = *(const float4*)(w_h + 8 * tid + 4);
    const float4 wg0 = *(const float4*)(w_g + 4 * tid);
    const float4 wg1 = *(const float4*)(w_g + 4 * tid + 1024);
    const float4 wg2 = *(const float4*)(w_g + 4 * tid + 2048);
    const float4 wg3 = *(const float4*)(w_g + 4 * tid + 3072);

    // ---- batch 0 data issued up front
    const float* hb = hints + (size_t)b0 * 2048;
    const float* gb = grid  + (size_t)b0 * 4096;
    float4 ch0 = *(const float4*)(hb + 8 * tid);
    float4 ch1 = *(const float4*)(hb + 8 * tid + 4);
    float4 cg0 = *(const float4*)(gb + 4 * tid);
    float4 cg1 = *(const float4*)(gb + 4 * tid + 1024);
    float4 cg2 = *(const float4*)(gb + 4 * tid + 2048);
    float4 cg3 = *(const float4*)(gb + 4 * tid + 3072);

    const int c0    = (tid & 15) * 4;
    const int rbase = tid >> 4;

    float total = 0.f;

    #pragma unroll
    for (int i = 0; i < BPB; ++i) {
        const int p = i & 1;

        // ---- hint phase: dot + row/col targets (thread = hint row tid>>1, half tid&1)
        float neural = ch0.x * wh0.x + ch0.y * wh0.y + ch0.z * wh0.z + ch0.w * wh0.w
                     + ch1.x * wh1.x + ch1.y * wh1.y + ch1.z * wh1.z + ch1.w * wh1.w;
        float hsum = ch0.x + ch0.y + ch0.z + ch0.w + ch1.x + ch1.y + ch1.z + ch1.w;
        hsum += __shfl_xor(hsum, 1);
        if ((tid & 1) == 0) target[p][tid >> 7][(tid >> 1) & 63] = hsum;
        __syncthreads();

        // ---- size: per-wave ballot (wave-uniform, no broadcast barrier)
        unsigned long long mr = __ballot(target[p][0][lane] > 0.f);
        unsigned long long mc = __ballot(target[p][1][lane] > 0.f);
        int lr = mr ? (63 - __builtin_clzll(mr)) : -1;
        int lc = mc ? (63 - __builtin_clzll(mc)) : -1;
        const int   size = (lr >= 0 && lc >= 0) ? (max(lr, lc) + 1) : 12;  // FALLBACK
        const float sz   = (float)size;

        const float mx = (c0 + 0 < size) ? 1.f : 0.f;
        const float my = (c0 + 1 < size) ? 1.f : 0.f;
        const float mz = (c0 + 2 < size) ? 1.f : 0.f;
        const float mw = (c0 + 3 < size) ? 1.f : 0.f;

        float binp = 0.f, errp = 0.f;
        float4 cacc = {0.f, 0.f, 0.f, 0.f};
        float4 gk[4] = {cg0, cg1, cg2, cg3};
        float4 wk[4] = {wg0, wg1, wg2, wg3};

        #pragma unroll
        for (int k = 0; k < 4; ++k) {
            float4 g = gk[k];
            float4 w = wk[k];
            neural += g.x * w.x + g.y * w.y + g.z * w.z + g.w * w.w;
            int   row   = rbase + 16 * k;
            float rmask = (row < size) ? 1.f : 0.f;
            binp += rmask * (mx * g.x * g.x + my * g.y * g.y + mz * g.z * g.z + mw * g.w * g.w);

            float sx  = __builtin_amdgcn_rcpf(1.f + __expf(-3.f * g.x));
            float sy  = __builtin_amdgcn_rcpf(1.f + __expf(-3.f * g.y));
            float sz_ = __builtin_amdgcn_rcpf(1.f + __expf(-3.f * g.z));
            float sw  = __builtin_amdgcn_rcpf(1.f + __expf(-3.f * g.w));

            float rs = mx * sx + my * sy + mz * sz_ + mw * sw;
            rs += __shfl_xor(rs, 1);
            rs += __shfl_xor(rs, 2);
            rs += __shfl_xor(rs, 4);
            rs += __shfl_xor(rs, 8);
            if ((lane & 15) == 0 && row < size) {
                float d = rs - target[p][0][row];
                errp += d * d;
            }

            cacc.x += rmask * sx;
            cacc.y += rmask * sy;
            cacc.z += rmask * sz_;
            cacc.w += rmask * sw;
        }

        // ---- prefetch next batch AFTER current regs are consumed (in-place
        // register reuse — no live-range doubling, unlike R3's spill).
        // Column phase + barriers below cover the load latency.
        if (i + 1 < BPB) {
            const float* hn = hints + (size_t)(b0 + i + 1) * 2048;
            const float* gn = grid  + (size_t)(b0 + i + 1) * 4096;
            ch0 = *(const float4*)(hn + 8 * tid);
            ch1 = *(const float4*)(hn + 8 * tid + 4);
            cg0 = *(const float4*)(gn + 4 * tid);
            cg1 = *(const float4*)(gn + 4 * tid + 1024);
            cg2 = *(const float4*)(gn + 4 * tid + 2048);
            cg3 = *(const float4*)(gn + 4 * tid + 3072);
        }

        // column partials across the 4 row-groups in this wave (stride-16 lanes)
        cacc.x += __shfl_xor(cacc.x, 16); cacc.x += __shfl_xor(cacc.x, 32);
        cacc.y += __shfl_xor(cacc.y, 16); cacc.y += __shfl_xor(cacc.y, 32);
        cacc.z += __shfl_xor(cacc.z, 16); cacc.z += __shfl_xor(cacc.z, 32);
        cacc.w += __shfl_xor(cacc.w, 16); cacc.w += __shfl_xor(cacc.w, 32);
        if (lane < 16) colp4[p][wv][lane] = cacc;
        __syncthreads();

        // column errors: 64 threads, one column each
        if (tid < 64) {
            const float* cp = (const float*)colp4[p];
            float csum = cp[tid] + cp[64 + tid] + cp[128 + tid] + cp[192 + tid];
            if (tid < size) {
                float d = csum - target[p][1][tid];
                errp += d * d;
            }
        }

        total += neural + errp * (10.f / sz) + binp * (0.1f / (sz * sz));
    }

    // ---- block reduce -> one partial per block (plain store, distinct lines)
    float v = total;
    #pragma unroll
    for (int off = 1; off < 64; off <<= 1) v += __shfl_xor(v, off);
    if (lane == 0) red[wv] = v;
    __syncthreads();
    if (tid == 0) ws[blockIdx.x] = red[0] + red[1] + red[2] + red[3];
}

__global__ __launch_bounds__(512) void final_reduce_kernel(
    const float* __restrict__ ws, float* __restrict__ out)
{
    const int tid = threadIdx.x;
    float4 v4 = ((const float4*)ws)[tid];       // 2048 floats / 512 threads
    float v = v4.x + v4.y + v4.z + v4.w;
    #pragma unroll
    for (int off = 1; off < 64; off <<= 1) v += __shfl_xor(v, off);
    __shared__ float r[8];
    if ((tid & 63) == 0) r[tid >> 6] = v;
    __syncthreads();
    if (tid < 8) {
        float t = r[tid];
        t += __shfl_xor(t, 1);
        t += __shfl_xor(t, 2);
        t += __shfl_xor(t, 4);
        if (tid == 0) out[0] = t * (1.f / (float)B_TOT);
    }
}

extern "C" void kernel_launch(void* const* d_in, const int* in_sizes, int n_in,
                              void* d_out, int out_size, void* d_ws, size_t ws_size,
                              hipStream_t stream) {
    const float* grid_p  = (const float*)d_in[0];
    const float* hints_p = (const float*)d_in[1];
    const float* w_g     = (const float*)d_in[2];
    const float* w_h     = (const float*)d_in[3];
    float* out = (float*)d_out;
    float* ws  = (float*)d_ws;

    energy_kernel<<<NBLK, 256, 0, stream>>>(grid_p, hints_p, w_g, w_h, ws);
    final_reduce_kernel<<<1, 512, 0, stream>>>(ws, out);
}